// Round 2
// baseline (442.092 us; speedup 1.0000x reference)
//
#include <hip/hip_runtime.h>
#include <hip/hip_bf16.h>

typedef __hip_bfloat16 bf16;
typedef short bf16x8 __attribute__((ext_vector_type(8)));
typedef float f32x4 __attribute__((ext_vector_type(4)));

#define IN_CH 64
#define HID 32
#define HEADS 4
#define C1 128   // HEADS*HID
#define OUTC 32
#define NEGSLOPE 0.2f

__device__ __forceinline__ float lrelu(float v) { return v > 0.f ? v : NEGSLOPE * v; }
__device__ __forceinline__ float elu(float v) { return v > 0.f ? v : __expf(v) - 1.f; }
__device__ __forceinline__ float lo16f(unsigned u) { return __uint_as_float(u << 16); }
__device__ __forceinline__ float hi16f(unsigned u) { return __uint_as_float(u & 0xFFFF0000u); }
__device__ __forceinline__ short f2bs(float f) {
  bf16 b = __float2bfloat16(f);
  return *reinterpret_cast<short*>(&b);
}
__device__ __forceinline__ unsigned pack2(float lo, float hi) {
  unsigned short l = (unsigned short)f2bs(lo);
  unsigned short h = (unsigned short)f2bs(hi);
  return ((unsigned)h << 16) | (unsigned)l;
}

// edge layout: [src(E) | dst(E)] halves, int32 (validated R11)

// ---------------- CSR build, XCD-sharded by dst range (validated R14) ----------------

__global__ __launch_bounds__(256) void k_degree(const int* __restrict__ w,
                                                int* __restrict__ deg, int E, int nN) {
  int xcd = blockIdx.x & 7;
  int gb = blockIdx.x >> 3;
  int nBlk = gridDim.x >> 3;
  int nPer = (nN + 7) >> 3;
  int lo = xcd * nPer, hi = min(nN, lo + nPer);
  const int* dst = w + E;
  for (int e = gb * 256 + threadIdx.x; e < E; e += nBlk * 256) {
    int d = dst[e];
    if (d >= lo && d < hi) atomicAdd(&deg[d], 1);
  }
}

__global__ void k_scan1(const int* __restrict__ deg, int* __restrict__ rp,
                        int* __restrict__ bsums, int n) {
  __shared__ int sm[256];
  int t = threadIdx.x;
  int i = blockIdx.x * 256 + t;
  int v = (i < n) ? deg[i] : 0;
  sm[t] = v;
  __syncthreads();
  #pragma unroll
  for (int off = 1; off < 256; off <<= 1) {
    int tv = (t >= off) ? sm[t - off] : 0;
    __syncthreads();
    sm[t] += tv;
    __syncthreads();
  }
  if (i < n) rp[i] = sm[t] - v;
  if (t == 255) bsums[blockIdx.x] = sm[255];
}

__global__ void k_scan2(int* __restrict__ bs, int nc) {
  __shared__ int sm[512];
  int t = threadIdx.x;
  int v = (t < nc) ? bs[t] : 0;
  sm[t] = v;
  __syncthreads();
  #pragma unroll
  for (int off = 1; off < 512; off <<= 1) {
    int tv = (t >= off) ? sm[t - off] : 0;
    __syncthreads();
    sm[t] += tv;
    __syncthreads();
  }
  if (t < nc) bs[t] = sm[t] - v;
}

__global__ void k_scan3(int* __restrict__ rp, int* __restrict__ cur,
                        const int* __restrict__ bs, int n, int E) {
  int i = blockIdx.x * 256 + threadIdx.x;
  if (i < n) {
    int r = rp[i] + bs[blockIdx.x];
    rp[i] = r;
    cur[i] = r;
  }
  if (i == 0) rp[n] = E;
}

__global__ __launch_bounds__(256) void k_scatter(const int* __restrict__ w,
                                                 int* __restrict__ cur,
                                                 int* __restrict__ csr, int E, int nN) {
  int xcd = blockIdx.x & 7;
  int gb = blockIdx.x >> 3;
  int nBlk = gridDim.x >> 3;
  int nPer = (nN + 7) >> 3;
  int lo = xcd * nPer, hi = min(nN, lo + nPer);
  const int* src = w;
  const int* dst = w + E;
  for (int e = gb * 256 + threadIdx.x; e < E; e += nBlk * 256) {
    int d = dst[e];
    if (d >= lo && d < hi) {
      int p = atomicAdd(&cur[d], 1);
      csr[p] = src[e];
    }
  }
}

// ---------------- k1: MFMA 16x16x32 bf16 — wave per 16-node tile ----------------
__global__ __launch_bounds__(256) void k1(
    const float* __restrict__ x, const float* __restrict__ W1,
    const float* __restrict__ attS, const float* __restrict__ attD,
    bf16* __restrict__ hB, float* __restrict__ alS, float* __restrict__ alD, int nN) {
  int lane = threadIdx.x & 63;
  int m = lane & 15;
  int q = lane >> 4;
  int wid = (blockIdx.x * 256 + threadIdx.x) >> 6;
  int nW = gridDim.x * 4;
  bf16x8 wf[8][2];
  #pragma unroll
  for (int ct = 0; ct < 8; ++ct)
    #pragma unroll
    for (int ks = 0; ks < 2; ++ks)
      #pragma unroll
      for (int j = 0; j < 8; ++j)
        wf[ct][ks][j] = f2bs(W1[(ks * 32 + q * 8 + j) * C1 + ct * 16 + m]);
  float aS[8], aD[8];
  #pragma unroll
  for (int ct = 0; ct < 8; ++ct) {
    int g = ct >> 1;
    int cc = (ct & 1) * 16 + m;
    aS[ct] = attS[g * HID + cc];
    aD[ct] = attD[g * HID + cc];
  }
  int nT = nN >> 4;
  for (int nt = wid; nt < nT; nt += nW) {
    int n0 = nt * 16;
    const float* xr = x + (size_t)(n0 + m) * IN_CH;
    bf16x8 af[2];
    #pragma unroll
    for (int ks = 0; ks < 2; ++ks) {
      float4 v0 = *(const float4*)(xr + ks * 32 + q * 8);
      float4 v1 = *(const float4*)(xr + ks * 32 + q * 8 + 4);
      af[ks][0] = f2bs(v0.x); af[ks][1] = f2bs(v0.y);
      af[ks][2] = f2bs(v0.z); af[ks][3] = f2bs(v0.w);
      af[ks][4] = f2bs(v1.x); af[ks][5] = f2bs(v1.y);
      af[ks][6] = f2bs(v1.z); af[ks][7] = f2bs(v1.w);
    }
    f32x4 acc[8];
    #pragma unroll
    for (int ct = 0; ct < 8; ++ct) acc[ct] = (f32x4){0.f, 0.f, 0.f, 0.f};
    #pragma unroll
    for (int ct = 0; ct < 8; ++ct) {
      acc[ct] = __builtin_amdgcn_mfma_f32_16x16x32_bf16(af[0], wf[ct][0], acc[ct], 0, 0, 0);
      acc[ct] = __builtin_amdgcn_mfma_f32_16x16x32_bf16(af[1], wf[ct][1], acc[ct], 0, 0, 0);
    }
    float pS[4][4], pD[4][4];
    #pragma unroll
    for (int g = 0; g < 4; ++g)
      #pragma unroll
      for (int r = 0; r < 4; ++r) { pS[g][r] = 0.f; pD[g][r] = 0.f; }
    #pragma unroll
    for (int ct = 0; ct < 8; ++ct) {
      int g = ct >> 1;
      #pragma unroll
      for (int r = 0; r < 4; ++r) {
        float v = acc[ct][r];
        hB[(size_t)(n0 + q * 4 + r) * C1 + ct * 16 + m] = __float2bfloat16(v);
        pS[g][r] += v * aS[ct];
        pD[g][r] += v * aD[ct];
      }
    }
    #pragma unroll
    for (int off = 1; off < 16; off <<= 1) {
      #pragma unroll
      for (int g = 0; g < 4; ++g)
        #pragma unroll
        for (int r = 0; r < 4; ++r) {
          pS[g][r] += __shfl_xor(pS[g][r], off);
          pD[g][r] += __shfl_xor(pD[g][r], off);
        }
    }
    if (m == 0) {
      #pragma unroll
      for (int r = 0; r < 4; ++r) {
        int n = n0 + q * 4 + r;
        #pragma unroll
        for (int g = 0; g < 4; ++g) {
          alS[(size_t)n * 4 + g] = pS[g][r];
          alD[(size_t)n * 4 + g] = pD[g][r];
        }
      }
    }
  }
}

// ---------------- k2 (R17): 16 lanes per node — coalesced 256B/edge gather ----------
// lane l16 = t&15 owns 8 hidden channels [l16*8, l16*8+8); g = l16>>2 is its head.
// Per edge: one uint4 load per lane (16 lanes cover the full 256B hB row contiguously).
// W2 staged in LDS with XOR swizzle on the float4 index (natural lane stride = 8 rows
// x 32 floats -> all 16 lanes on bank 0 without it).
__global__ __launch_bounds__(256) void k2(
    const unsigned* __restrict__ hb, const float* __restrict__ alS, const float* __restrict__ alD,
    const int* __restrict__ rp, const int* __restrict__ csr,
    const float* __restrict__ b1, const float* __restrict__ W2,
    const float* __restrict__ attS2, const float* __restrict__ attD2,
    bf16* __restrict__ h2B, float* __restrict__ alS2, float* __restrict__ alD2, int nN) {
  __shared__ float w2s[C1 * OUTC];  // 16 KB, swizzled
  for (int i = threadIdx.x; i < C1 * OUTC; i += 256) {
    int k = i >> 5;
    int ch = i & 31;
    int ch4 = ch >> 2;
    int cl = ch & 3;
    int s = (k >> 3) & 7;
    // float4-group ch4 of row k stored at position ch4^s
    w2s[(k << 5) + (((ch4 ^ s) << 2) | cl)] = W2[i];
  }
  __syncthreads();
  int t = blockIdx.x * 256 + threadIdx.x;
  if (t >= nN * 16) return;
  int n = t >> 4;
  int l16 = t & 15;
  int g = l16 >> 2;
  int rs = rp[n], re = rp[n + 1];
  float ad = alD[(size_t)n * HEADS + g];
  float acc[8];
  #pragma unroll
  for (int c = 0; c < 8; ++c) acc[c] = 0.f;
  float denom = 0.f;
  {  // self-loop
    float wv = __expf(lrelu(alS[(size_t)n * HEADS + g] + ad));
    denom += wv;
    uint4 qq = *(const uint4*)(hb + (size_t)n * 64 + l16 * 4);
    acc[0] += wv * lo16f(qq.x); acc[1] += wv * hi16f(qq.x);
    acc[2] += wv * lo16f(qq.y); acc[3] += wv * hi16f(qq.y);
    acc[4] += wv * lo16f(qq.z); acc[5] += wv * hi16f(qq.z);
    acc[6] += wv * lo16f(qq.w); acc[7] += wv * hi16f(qq.w);
  }
  for (int i = rs; i < re; ++i) {
    int s = csr[i];
    float wv = __expf(lrelu(alS[(size_t)s * HEADS + g] + ad));
    denom += wv;
    uint4 qq = *(const uint4*)(hb + (size_t)s * 64 + l16 * 4);
    acc[0] += wv * lo16f(qq.x); acc[1] += wv * hi16f(qq.x);
    acc[2] += wv * lo16f(qq.y); acc[3] += wv * hi16f(qq.y);
    acc[4] += wv * lo16f(qq.z); acc[5] += wv * hi16f(qq.z);
    acc[6] += wv * lo16f(qq.w); acc[7] += wv * hi16f(qq.w);
  }
  float inv = 1.f / denom;
  #pragma unroll
  for (int c = 0; c < 8; ++c)
    acc[c] = elu(acc[c] * inv + b1[l16 * 8 + c]);
  // fused layer-2 GEMM: each lane holds 8 k's (k = l16*8+c); partial over all 32 outputs.
  // Read position jq^sw of row k holds original float4-group (jq^sw)^s == jq (sw==s here).
  float partial[OUTC];
  #pragma unroll
  for (int j = 0; j < OUTC; ++j) partial[j] = 0.f;
  int sw = l16 & 7;
  #pragma unroll
  for (int c = 0; c < 8; ++c) {
    float v = acc[c];
    const float* wrow = &w2s[(l16 * 8 + c) << 5];
    #pragma unroll
    for (int jq = 0; jq < 8; ++jq) {
      float4 wq = *(const float4*)(wrow + ((jq ^ sw) << 2));
      partial[jq * 4 + 0] += v * wq.x;
      partial[jq * 4 + 1] += v * wq.y;
      partial[jq * 4 + 2] += v * wq.z;
      partial[jq * 4 + 3] += v * wq.w;
    }
  }
  #pragma unroll
  for (int off = 1; off < 16; off <<= 1) {
    #pragma unroll
    for (int j = 0; j < OUTC; ++j)
      partial[j] += __shfl_xor(partial[j], off);
  }
  if (l16 < 4) {
    uint4 uu;
    uu.x = pack2(partial[l16 * 8 + 0], partial[l16 * 8 + 1]);
    uu.y = pack2(partial[l16 * 8 + 2], partial[l16 * 8 + 3]);
    uu.z = pack2(partial[l16 * 8 + 4], partial[l16 * 8 + 5]);
    uu.w = pack2(partial[l16 * 8 + 6], partial[l16 * 8 + 7]);
    *reinterpret_cast<uint4*>(h2B + (size_t)n * OUTC + l16 * 8) = uu;
  }
  if (l16 == 0) {
    float ps = 0.f, pd = 0.f;
    #pragma unroll
    for (int j = 0; j < OUTC; ++j) {
      ps += partial[j] * attS2[j];
      pd += partial[j] * attD2[j];
    }
    alS2[n] = ps;
    alD2[n] = pd;
  }
}

// ---------------- k4 (R17): 4 lanes per node layer-2 aggregate -> out fp32 ----------
__global__ __launch_bounds__(256) void k4(
    const unsigned* __restrict__ h2b, const float* __restrict__ alS2,
    const float* __restrict__ alD2, const int* __restrict__ rp, const int* __restrict__ csr,
    const float* __restrict__ b2, float* __restrict__ out, int nN) {
  int t = blockIdx.x * 256 + threadIdx.x;
  if (t >= nN * 4) return;
  int n = t >> 2;
  int j = t & 3;
  int rs = rp[n], re = rp[n + 1];
  float ad = alD2[n];
  float acc[8];
  #pragma unroll
  for (int c = 0; c < 8; ++c) acc[c] = 0.f;
  float denom = 0.f;
  {  // self-loop
    float wv = __expf(lrelu(alS2[n] + ad));
    denom += wv;
    uint4 qq = *(const uint4*)(h2b + (size_t)n * 16 + j * 4);
    acc[0] += wv * lo16f(qq.x); acc[1] += wv * hi16f(qq.x);
    acc[2] += wv * lo16f(qq.y); acc[3] += wv * hi16f(qq.y);
    acc[4] += wv * lo16f(qq.z); acc[5] += wv * hi16f(qq.z);
    acc[6] += wv * lo16f(qq.w); acc[7] += wv * hi16f(qq.w);
  }
  for (int i = rs; i < re; ++i) {
    int s = csr[i];
    float wv = __expf(lrelu(alS2[s] + ad));
    denom += wv;
    uint4 qq = *(const uint4*)(h2b + (size_t)s * 16 + j * 4);
    acc[0] += wv * lo16f(qq.x); acc[1] += wv * hi16f(qq.x);
    acc[2] += wv * lo16f(qq.y); acc[3] += wv * hi16f(qq.y);
    acc[4] += wv * lo16f(qq.z); acc[5] += wv * hi16f(qq.z);
    acc[6] += wv * lo16f(qq.w); acc[7] += wv * hi16f(qq.w);
  }
  float inv = 1.f / denom;
  float4 o0, o1;
  o0.x = acc[0] * inv + b2[j * 8 + 0];
  o0.y = acc[1] * inv + b2[j * 8 + 1];
  o0.z = acc[2] * inv + b2[j * 8 + 2];
  o0.w = acc[3] * inv + b2[j * 8 + 3];
  o1.x = acc[4] * inv + b2[j * 8 + 4];
  o1.y = acc[5] * inv + b2[j * 8 + 5];
  o1.z = acc[6] * inv + b2[j * 8 + 6];
  o1.w = acc[7] * inv + b2[j * 8 + 7];
  *(float4*)(out + (size_t)n * OUTC + j * 8) = o0;
  *(float4*)(out + (size_t)n * OUTC + j * 8 + 4) = o1;
}

// ---------------- launch ----------------

extern "C" void kernel_launch(void* const* d_in, const int* in_sizes, int n_in,
                              void* d_out, int out_size, void* d_ws, size_t ws_size,
                              hipStream_t stream) {
  {
    const int expect[10] = {6400000, 3200000, 8192, 128, 128, 128, 4096, 32, 32, 32};
    bool ok = (n_in == 10) && (out_size == 3200000);
    for (int i = 0; i < 10 && ok; ++i) ok = (in_sizes[i] == expect[i]);
    if (!ok) { *(volatile int*)0 = 1; }
  }

  const float* x     = (const float*)d_in[0];
  const int*   ew    = (const int*)d_in[1];
  const float* W1    = (const float*)d_in[2];
  const float* attS1 = (const float*)d_in[3];
  const float* attD1 = (const float*)d_in[4];
  const float* b1    = (const float*)d_in[5];
  const float* W2    = (const float*)d_in[6];
  const float* attS2 = (const float*)d_in[7];
  const float* attD2 = (const float*)d_in[8];
  const float* b2    = (const float*)d_in[9];
  float* out = (float*)d_out;

  const int nN = in_sizes[0] / IN_CH;   // 100000
  const int E  = in_sizes[1] / 2;       // 1600000

  auto ALN = [](size_t v) { return (v + 255) & ~(size_t)255; };
  char* p = (char*)d_ws;
  bf16*  hB   = (bf16*)p;  p += ALN((size_t)nN * C1 * 2);
  float* alS1v= (float*)p; p += ALN((size_t)nN * 4 * 4);
  float* alD1v= (float*)p; p += ALN((size_t)nN * 4 * 4);
  bf16*  h2B  = (bf16*)p;  p += ALN((size_t)nN * OUTC * 2);
  float* alS2v= (float*)p; p += ALN((size_t)nN * 4);
  float* alD2v= (float*)p; p += ALN((size_t)nN * 4);
  int* deg    = (int*)p;   p += ALN((size_t)nN * 4);
  int* rp     = (int*)p;   p += ALN((size_t)(nN + 1) * 4);
  int* cur    = (int*)p;   p += ALN((size_t)nN * 4);
  int* bs     = (int*)p;   p += ALN(1024 * 4);
  int* csr    = (int*)p;   p += ALN((size_t)E * 4);
  if ((size_t)(p - (char*)d_ws) > ws_size) { *(volatile int*)0 = 2; }

  const int nChunks = (nN + 255) / 256;  // 391

  hipMemsetAsync(deg, 0, (size_t)nN * 4, stream);
  k_degree<<<1024, 256, 0, stream>>>(ew, deg, E, nN);
  k_scan1<<<nChunks, 256, 0, stream>>>(deg, rp, bs, nN);
  k_scan2<<<1, 512, 0, stream>>>(bs, nChunks);
  k_scan3<<<nChunks, 256, 0, stream>>>(rp, cur, bs, nN, E);
  k_scatter<<<1024, 256, 0, stream>>>(ew, cur, csr, E, nN);
  k1<<<512, 256, 0, stream>>>(x, W1, attS1, attD1, hB, alS1v, alD1v, nN);
  k2<<<(nN * 16 + 255) / 256, 256, 0, stream>>>((const unsigned*)hB, alS1v, alD1v,
                                                rp, csr, b1, W2, attS2, attD2,
                                                h2B, alS2v, alD2v, nN);
  k4<<<(nN * 4 + 255) / 256, 256, 0, stream>>>((const unsigned*)h2B, alS2v, alD2v,
                                               rp, csr, b2, out, nN);
}

// Round 3
// 377.913 us; speedup vs baseline: 1.1698x; 1.1698x over previous
//
#include <hip/hip_runtime.h>
#include <hip/hip_bf16.h>

typedef __hip_bfloat16 bf16;
typedef short bf16x8 __attribute__((ext_vector_type(8)));
typedef float f32x4 __attribute__((ext_vector_type(4)));

#define IN_CH 64
#define HID 32
#define HEADS 4
#define C1 128   // HEADS*HID
#define OUTC 32
#define NEGSLOPE 0.2f

__device__ __forceinline__ float lrelu(float v) { return v > 0.f ? v : NEGSLOPE * v; }
__device__ __forceinline__ float elu(float v) { return v > 0.f ? v : __expf(v) - 1.f; }
__device__ __forceinline__ float lo16f(unsigned u) { return __uint_as_float(u << 16); }
__device__ __forceinline__ float hi16f(unsigned u) { return __uint_as_float(u & 0xFFFF0000u); }
__device__ __forceinline__ short f2bs(float f) {
  bf16 b = __float2bfloat16(f);
  return *reinterpret_cast<short*>(&b);
}
__device__ __forceinline__ unsigned pack2(float lo, float hi) {
  unsigned short l = (unsigned short)f2bs(lo);
  unsigned short h = (unsigned short)f2bs(hi);
  return ((unsigned)h << 16) | (unsigned)l;
}

// edge layout: [src(E) | dst(E)] halves, int32 (validated R11)

// ---------------- CSR build, XCD-sharded by dst range (validated R14) ----------------

__global__ __launch_bounds__(256) void k_degree(const int* __restrict__ w,
                                                int* __restrict__ deg, int E, int nN) {
  int xcd = blockIdx.x & 7;
  int gb = blockIdx.x >> 3;
  int nBlk = gridDim.x >> 3;
  int nPer = (nN + 7) >> 3;
  int lo = xcd * nPer, hi = min(nN, lo + nPer);
  const int* dst = w + E;
  for (int e = gb * 256 + threadIdx.x; e < E; e += nBlk * 256) {
    int d = dst[e];
    if (d >= lo && d < hi) atomicAdd(&deg[d], 1);
  }
}

__global__ void k_scan1(const int* __restrict__ deg, int* __restrict__ rp,
                        int* __restrict__ bsums, int n) {
  __shared__ int sm[256];
  int t = threadIdx.x;
  int i = blockIdx.x * 256 + t;
  int v = (i < n) ? deg[i] : 0;
  sm[t] = v;
  __syncthreads();
  #pragma unroll
  for (int off = 1; off < 256; off <<= 1) {
    int tv = (t >= off) ? sm[t - off] : 0;
    __syncthreads();
    sm[t] += tv;
    __syncthreads();
  }
  if (i < n) rp[i] = sm[t] - v;
  if (t == 255) bsums[blockIdx.x] = sm[255];
}

__global__ void k_scan2(int* __restrict__ bs, int nc) {
  __shared__ int sm[512];
  int t = threadIdx.x;
  int v = (t < nc) ? bs[t] : 0;
  sm[t] = v;
  __syncthreads();
  #pragma unroll
  for (int off = 1; off < 512; off <<= 1) {
    int tv = (t >= off) ? sm[t - off] : 0;
    __syncthreads();
    sm[t] += tv;
    __syncthreads();
  }
  if (t < nc) bs[t] = sm[t] - v;
}

__global__ void k_scan3(int* __restrict__ rp, int* __restrict__ cur,
                        const int* __restrict__ bs, int n, int E) {
  int i = blockIdx.x * 256 + threadIdx.x;
  if (i < n) {
    int r = rp[i] + bs[blockIdx.x];
    rp[i] = r;
    cur[i] = r;
  }
  if (i == 0) rp[n] = E;
}

__global__ __launch_bounds__(256) void k_scatter(const int* __restrict__ w,
                                                 int* __restrict__ cur,
                                                 int* __restrict__ csr, int E, int nN) {
  int xcd = blockIdx.x & 7;
  int gb = blockIdx.x >> 3;
  int nBlk = gridDim.x >> 3;
  int nPer = (nN + 7) >> 3;
  int lo = xcd * nPer, hi = min(nN, lo + nPer);
  const int* src = w;
  const int* dst = w + E;
  for (int e = gb * 256 + threadIdx.x; e < E; e += nBlk * 256) {
    int d = dst[e];
    if (d >= lo && d < hi) {
      int p = atomicAdd(&cur[d], 1);
      csr[p] = src[e];
    }
  }
}

// ---------------- k1: MFMA 16x16x32 bf16 — wave per 16-node tile ----------------
__global__ __launch_bounds__(256) void k1(
    const float* __restrict__ x, const float* __restrict__ W1,
    const float* __restrict__ attS, const float* __restrict__ attD,
    bf16* __restrict__ hB, float* __restrict__ alS, float* __restrict__ alD, int nN) {
  int lane = threadIdx.x & 63;
  int m = lane & 15;
  int q = lane >> 4;
  int wid = (blockIdx.x * 256 + threadIdx.x) >> 6;
  int nW = gridDim.x * 4;
  bf16x8 wf[8][2];
  #pragma unroll
  for (int ct = 0; ct < 8; ++ct)
    #pragma unroll
    for (int ks = 0; ks < 2; ++ks)
      #pragma unroll
      for (int j = 0; j < 8; ++j)
        wf[ct][ks][j] = f2bs(W1[(ks * 32 + q * 8 + j) * C1 + ct * 16 + m]);
  float aS[8], aD[8];
  #pragma unroll
  for (int ct = 0; ct < 8; ++ct) {
    int g = ct >> 1;
    int cc = (ct & 1) * 16 + m;
    aS[ct] = attS[g * HID + cc];
    aD[ct] = attD[g * HID + cc];
  }
  int nT = nN >> 4;
  for (int nt = wid; nt < nT; nt += nW) {
    int n0 = nt * 16;
    const float* xr = x + (size_t)(n0 + m) * IN_CH;
    bf16x8 af[2];
    #pragma unroll
    for (int ks = 0; ks < 2; ++ks) {
      float4 v0 = *(const float4*)(xr + ks * 32 + q * 8);
      float4 v1 = *(const float4*)(xr + ks * 32 + q * 8 + 4);
      af[ks][0] = f2bs(v0.x); af[ks][1] = f2bs(v0.y);
      af[ks][2] = f2bs(v0.z); af[ks][3] = f2bs(v0.w);
      af[ks][4] = f2bs(v1.x); af[ks][5] = f2bs(v1.y);
      af[ks][6] = f2bs(v1.z); af[ks][7] = f2bs(v1.w);
    }
    f32x4 acc[8];
    #pragma unroll
    for (int ct = 0; ct < 8; ++ct) acc[ct] = (f32x4){0.f, 0.f, 0.f, 0.f};
    #pragma unroll
    for (int ct = 0; ct < 8; ++ct) {
      acc[ct] = __builtin_amdgcn_mfma_f32_16x16x32_bf16(af[0], wf[ct][0], acc[ct], 0, 0, 0);
      acc[ct] = __builtin_amdgcn_mfma_f32_16x16x32_bf16(af[1], wf[ct][1], acc[ct], 0, 0, 0);
    }
    float pS[4][4], pD[4][4];
    #pragma unroll
    for (int g = 0; g < 4; ++g)
      #pragma unroll
      for (int r = 0; r < 4; ++r) { pS[g][r] = 0.f; pD[g][r] = 0.f; }
    #pragma unroll
    for (int ct = 0; ct < 8; ++ct) {
      int g = ct >> 1;
      #pragma unroll
      for (int r = 0; r < 4; ++r) {
        float v = acc[ct][r];
        hB[(size_t)(n0 + q * 4 + r) * C1 + ct * 16 + m] = __float2bfloat16(v);
        pS[g][r] += v * aS[ct];
        pD[g][r] += v * aD[ct];
      }
    }
    #pragma unroll
    for (int off = 1; off < 16; off <<= 1) {
      #pragma unroll
      for (int g = 0; g < 4; ++g)
        #pragma unroll
        for (int r = 0; r < 4; ++r) {
          pS[g][r] += __shfl_xor(pS[g][r], off);
          pD[g][r] += __shfl_xor(pD[g][r], off);
        }
    }
    if (m == 0) {
      #pragma unroll
      for (int r = 0; r < 4; ++r) {
        int n = n0 + q * 4 + r;
        #pragma unroll
        for (int g = 0; g < 4; ++g) {
          alS[(size_t)n * 4 + g] = pS[g][r];
          alD[(size_t)n * 4 + g] = pD[g][r];
        }
      }
    }
  }
}

// ---------------- k2 (R18): thread = (node, head, quarter) ----------------
// Lane layout: g = lane&3 (head), qt = (lane>>2)&3 (edge-list quarter), node = t>>4.
// Each thread walks edges rs+qt, rs+qt+4, ... — exp computed exactly once per
// (edge, head); 4x resident waves and ~4x shorter serial loops vs R16.
// Quarter-reduce (xor 4,8) -> full acc; ELU; GEMM split over 4 output-column
// quarters (32k x 8j per lane); head-reduce (xor 1,2) -> final out columns.
// W2 LDS swizzle: float4-group ch4 of row k stored at ch4 ^ (k>>5) so the 16
// distinct (g,qt) read addresses spread over 8 bank-quads (2-way, free).
__global__ __launch_bounds__(256) void k2(
    const unsigned* __restrict__ hb, const float* __restrict__ alS, const float* __restrict__ alD,
    const int* __restrict__ rp, const int* __restrict__ csr,
    const float* __restrict__ b1, const float* __restrict__ W2,
    const float* __restrict__ attS2, const float* __restrict__ attD2,
    bf16* __restrict__ h2B, float* __restrict__ alS2, float* __restrict__ alD2, int nN) {
  __shared__ float w2s[C1 * OUTC];  // 16 KB
  for (int i = threadIdx.x; i < C1 * OUTC; i += 256) {
    int k = i >> 5;
    int ch = i & 31;
    int ch4 = ch >> 2;
    int cl = ch & 3;
    int sw = k >> 5;  // head index of this row, 0..3
    w2s[(k << 5) + (((ch4 ^ sw) << 2) | cl)] = W2[i];
  }
  __syncthreads();
  int t = blockIdx.x * 256 + threadIdx.x;  // grid is exactly nN*16 threads
  int n = t >> 4;
  int g = t & 3;
  int qt = (t >> 2) & 3;
  int rs = rp[n], re = rp[n + 1];
  float ad = alD[(size_t)n * HEADS + g];
  float acc[HID];
  #pragma unroll
  for (int c = 0; c < HID; ++c) acc[c] = 0.f;
  float denom = 0.f;
  if (qt == 0) {  // self-loop handled by quarter 0
    float wv = __expf(lrelu(alS[(size_t)n * HEADS + g] + ad));
    denom += wv;
    const uint4* hr = (const uint4*)(hb + (size_t)n * 64 + g * 16);
    #pragma unroll
    for (int qq2 = 0; qq2 < 4; ++qq2) {
      uint4 qq = hr[qq2];
      acc[qq2 * 8 + 0] += wv * lo16f(qq.x); acc[qq2 * 8 + 1] += wv * hi16f(qq.x);
      acc[qq2 * 8 + 2] += wv * lo16f(qq.y); acc[qq2 * 8 + 3] += wv * hi16f(qq.y);
      acc[qq2 * 8 + 4] += wv * lo16f(qq.z); acc[qq2 * 8 + 5] += wv * hi16f(qq.z);
      acc[qq2 * 8 + 6] += wv * lo16f(qq.w); acc[qq2 * 8 + 7] += wv * hi16f(qq.w);
    }
  }
  for (int i = rs + qt; i < re; i += 4) {
    int s = csr[i];
    float wv = __expf(lrelu(alS[(size_t)s * HEADS + g] + ad));
    denom += wv;
    const uint4* hr = (const uint4*)(hb + (size_t)s * 64 + g * 16);
    #pragma unroll
    for (int qq2 = 0; qq2 < 4; ++qq2) {
      uint4 qq = hr[qq2];
      acc[qq2 * 8 + 0] += wv * lo16f(qq.x); acc[qq2 * 8 + 1] += wv * hi16f(qq.x);
      acc[qq2 * 8 + 2] += wv * lo16f(qq.y); acc[qq2 * 8 + 3] += wv * hi16f(qq.y);
      acc[qq2 * 8 + 4] += wv * lo16f(qq.z); acc[qq2 * 8 + 5] += wv * hi16f(qq.z);
      acc[qq2 * 8 + 6] += wv * lo16f(qq.w); acc[qq2 * 8 + 7] += wv * hi16f(qq.w);
    }
  }
  // reduce over quarters (lane bits 2,3) — butterfly leaves sums in all lanes
  denom += __shfl_xor(denom, 4);
  denom += __shfl_xor(denom, 8);
  #pragma unroll
  for (int c = 0; c < HID; ++c) {
    acc[c] += __shfl_xor(acc[c], 4);
    acc[c] += __shfl_xor(acc[c], 8);
  }
  float inv = 1.f / denom;
  #pragma unroll
  for (int c = 0; c < HID; ++c)
    acc[c] = elu(acc[c] * inv + b1[g * HID + c]);
  // fused layer-2 GEMM: this lane computes j in [qt*8, qt*8+8) over its head's 32 k
  float partial[8];
  #pragma unroll
  for (int j = 0; j < 8; ++j) partial[j] = 0.f;
  #pragma unroll
  for (int kk = 0; kk < HID; ++kk) {
    float v = acc[kk];
    int base = (g * HID + kk) << 5;
    float4 w0 = *(const float4*)&w2s[base + (((qt * 2 + 0) ^ g) << 2)];
    float4 w1 = *(const float4*)&w2s[base + (((qt * 2 + 1) ^ g) << 2)];
    partial[0] += v * w0.x; partial[1] += v * w0.y;
    partial[2] += v * w0.z; partial[3] += v * w0.w;
    partial[4] += v * w1.x; partial[5] += v * w1.y;
    partial[6] += v * w1.z; partial[7] += v * w1.w;
  }
  // reduce over heads (lane bits 0,1)
  #pragma unroll
  for (int j = 0; j < 8; ++j) {
    partial[j] += __shfl_xor(partial[j], 1);
    partial[j] += __shfl_xor(partial[j], 2);
  }
  // layer-2 logits: dot with att over this lane's j-range, reduce over quarters
  float ps = 0.f, pd = 0.f;
  #pragma unroll
  for (int j = 0; j < 8; ++j) {
    ps += partial[j] * attS2[qt * 8 + j];
    pd += partial[j] * attD2[qt * 8 + j];
  }
  ps += __shfl_xor(ps, 4); ps += __shfl_xor(ps, 8);
  pd += __shfl_xor(pd, 4); pd += __shfl_xor(pd, 8);
  if ((t & 15) == 0) {
    alS2[n] = ps;
    alD2[n] = pd;
  }
  if (g == 0) {  // one writer per (node, quarter): 16B each, 64B contiguous per node
    uint4 uu;
    uu.x = pack2(partial[0], partial[1]);
    uu.y = pack2(partial[2], partial[3]);
    uu.z = pack2(partial[4], partial[5]);
    uu.w = pack2(partial[6], partial[7]);
    *reinterpret_cast<uint4*>(h2B + (size_t)n * OUTC + qt * 8) = uu;
  }
}

// ---------------- k4 (R18): thread = (node, quarter) -> out fp32 ----------------
__global__ __launch_bounds__(256) void k4(
    const unsigned* __restrict__ h2b, const float* __restrict__ alS2,
    const float* __restrict__ alD2, const int* __restrict__ rp, const int* __restrict__ csr,
    const float* __restrict__ b2, float* __restrict__ out, int nN) {
  int t = blockIdx.x * 256 + threadIdx.x;
  if (t >= nN * 4) return;  // nN*4 is wave-aligned (6250 full waves)
  int n = t >> 2;
  int qt = t & 3;
  int rs = rp[n], re = rp[n + 1];
  float ad = alD2[n];
  float acc[OUTC];
  #pragma unroll
  for (int c = 0; c < OUTC; ++c) acc[c] = 0.f;
  float denom = 0.f;
  if (qt == 0) {  // self-loop
    float wv = __expf(lrelu(alS2[n] + ad));
    denom += wv;
    const uint4* hr = (const uint4*)(h2b + (size_t)n * 16);
    #pragma unroll
    for (int q = 0; q < 4; ++q) {
      uint4 qq = hr[q];
      acc[q * 8 + 0] += wv * lo16f(qq.x); acc[q * 8 + 1] += wv * hi16f(qq.x);
      acc[q * 8 + 2] += wv * lo16f(qq.y); acc[q * 8 + 3] += wv * hi16f(qq.y);
      acc[q * 8 + 4] += wv * lo16f(qq.z); acc[q * 8 + 5] += wv * hi16f(qq.z);
      acc[q * 8 + 6] += wv * lo16f(qq.w); acc[q * 8 + 7] += wv * hi16f(qq.w);
    }
  }
  for (int i = rs + qt; i < re; i += 4) {
    int s = csr[i];
    float wv = __expf(lrelu(alS2[s] + ad));
    denom += wv;
    const uint4* hr = (const uint4*)(h2b + (size_t)s * 16);
    #pragma unroll
    for (int q = 0; q < 4; ++q) {
      uint4 qq = hr[q];
      acc[q * 8 + 0] += wv * lo16f(qq.x); acc[q * 8 + 1] += wv * hi16f(qq.x);
      acc[q * 8 + 2] += wv * lo16f(qq.y); acc[q * 8 + 3] += wv * hi16f(qq.y);
      acc[q * 8 + 4] += wv * lo16f(qq.z); acc[q * 8 + 5] += wv * hi16f(qq.z);
      acc[q * 8 + 6] += wv * lo16f(qq.w); acc[q * 8 + 7] += wv * hi16f(qq.w);
    }
  }
  // reduce over quarters (lane bits 0,1)
  denom += __shfl_xor(denom, 1);
  denom += __shfl_xor(denom, 2);
  #pragma unroll
  for (int c = 0; c < OUTC; ++c) {
    acc[c] += __shfl_xor(acc[c], 1);
    acc[c] += __shfl_xor(acc[c], 2);
  }
  float inv = 1.f / denom;
  int c0 = qt * 8;
  float4 o0, o1;
  o0.x = acc[c0 + 0] * inv + b2[c0 + 0];
  o0.y = acc[c0 + 1] * inv + b2[c0 + 1];
  o0.z = acc[c0 + 2] * inv + b2[c0 + 2];
  o0.w = acc[c0 + 3] * inv + b2[c0 + 3];
  o1.x = acc[c0 + 4] * inv + b2[c0 + 4];
  o1.y = acc[c0 + 5] * inv + b2[c0 + 5];
  o1.z = acc[c0 + 6] * inv + b2[c0 + 6];
  o1.w = acc[c0 + 7] * inv + b2[c0 + 7];
  *(float4*)(out + (size_t)n * OUTC + c0) = o0;
  *(float4*)(out + (size_t)n * OUTC + c0 + 4) = o1;
}

// ---------------- launch ----------------

extern "C" void kernel_launch(void* const* d_in, const int* in_sizes, int n_in,
                              void* d_out, int out_size, void* d_ws, size_t ws_size,
                              hipStream_t stream) {
  {
    const int expect[10] = {6400000, 3200000, 8192, 128, 128, 128, 4096, 32, 32, 32};
    bool ok = (n_in == 10) && (out_size == 3200000);
    for (int i = 0; i < 10 && ok; ++i) ok = (in_sizes[i] == expect[i]);
    if (!ok) { *(volatile int*)0 = 1; }
  }

  const float* x     = (const float*)d_in[0];
  const int*   ew    = (const int*)d_in[1];
  const float* W1    = (const float*)d_in[2];
  const float* attS1 = (const float*)d_in[3];
  const float* attD1 = (const float*)d_in[4];
  const float* b1    = (const float*)d_in[5];
  const float* W2    = (const float*)d_in[6];
  const float* attS2 = (const float*)d_in[7];
  const float* attD2 = (const float*)d_in[8];
  const float* b2    = (const float*)d_in[9];
  float* out = (float*)d_out;

  const int nN = in_sizes[0] / IN_CH;   // 100000
  const int E  = in_sizes[1] / 2;       // 1600000

  auto ALN = [](size_t v) { return (v + 255) & ~(size_t)255; };
  char* p = (char*)d_ws;
  bf16*  hB   = (bf16*)p;  p += ALN((size_t)nN * C1 * 2);
  float* alS1v= (float*)p; p += ALN((size_t)nN * 4 * 4);
  float* alD1v= (float*)p; p += ALN((size_t)nN * 4 * 4);
  bf16*  h2B  = (bf16*)p;  p += ALN((size_t)nN * OUTC * 2);
  float* alS2v= (float*)p; p += ALN((size_t)nN * 4);
  float* alD2v= (float*)p; p += ALN((size_t)nN * 4);
  int* deg    = (int*)p;   p += ALN((size_t)nN * 4);
  int* rp     = (int*)p;   p += ALN((size_t)(nN + 1) * 4);
  int* cur    = (int*)p;   p += ALN((size_t)nN * 4);
  int* bs     = (int*)p;   p += ALN(1024 * 4);
  int* csr    = (int*)p;   p += ALN((size_t)E * 4);
  if ((size_t)(p - (char*)d_ws) > ws_size) { *(volatile int*)0 = 2; }

  const int nChunks = (nN + 255) / 256;  // 391

  hipMemsetAsync(deg, 0, (size_t)nN * 4, stream);
  k_degree<<<1024, 256, 0, stream>>>(ew, deg, E, nN);
  k_scan1<<<nChunks, 256, 0, stream>>>(deg, rp, bs, nN);
  k_scan2<<<1, 512, 0, stream>>>(bs, nChunks);
  k_scan3<<<nChunks, 256, 0, stream>>>(rp, cur, bs, nN, E);
  k_scatter<<<1024, 256, 0, stream>>>(ew, cur, csr, E, nN);
  k1<<<512, 256, 0, stream>>>(x, W1, attS1, attD1, hB, alS1v, alD1v, nN);
  k2<<<(nN * 16) / 256, 256, 0, stream>>>((const unsigned*)hB, alS1v, alD1v,
                                          rp, csr, b1, W2, attS2, attD2,
                                          h2B, alS2v, alD2v, nN);
  k4<<<(nN * 4 + 255) / 256, 256, 0, stream>>>((const unsigned*)h2B, alS2v, alD2v,
                                               rp, csr, b2, out, nN);
}

// Round 4
// 376.003 us; speedup vs baseline: 1.1758x; 1.0051x over previous
//
#include <hip/hip_runtime.h>
#include <hip/hip_bf16.h>

typedef __hip_bfloat16 bf16;
typedef short bf16x8 __attribute__((ext_vector_type(8)));
typedef float f32x4 __attribute__((ext_vector_type(4)));
typedef float f32x2 __attribute__((ext_vector_type(2)));

#define IN_CH 64
#define HID 32
#define HEADS 4
#define C1 128   // HEADS*HID
#define OUTC 32
#define NEGSLOPE 0.2f

__device__ __forceinline__ float lrelu(float v) { return v > 0.f ? v : NEGSLOPE * v; }
__device__ __forceinline__ float elu(float v) { return v > 0.f ? v : __expf(v) - 1.f; }
__device__ __forceinline__ float lo16f(unsigned u) { return __uint_as_float(u << 16); }
__device__ __forceinline__ float hi16f(unsigned u) { return __uint_as_float(u & 0xFFFF0000u); }
__device__ __forceinline__ short f2bs(float f) {
  bf16 b = __float2bfloat16(f);
  return *reinterpret_cast<short*>(&b);
}
__device__ __forceinline__ unsigned pack2(float lo, float hi) {
  unsigned short l = (unsigned short)f2bs(lo);
  unsigned short h = (unsigned short)f2bs(hi);
  return ((unsigned)h << 16) | (unsigned)l;
}
// packed fp32 FMA: d = a*b + c componentwise (v_pk_fma_f32, VOP3P)
__device__ __forceinline__ f32x2 pkfma(f32x2 a, f32x2 b, f32x2 c) {
  f32x2 d;
  asm("v_pk_fma_f32 %0, %1, %2, %3" : "=v"(d) : "v"(a), "v"(b), "v"(c));
  return d;
}
// acc2[0..3] += wv2 * unpack8(qq)  (8 bf16 channels -> 4 packed FMAs)
__device__ __forceinline__ void mac4(f32x2* acc2, f32x2 wv2, uint4 qq) {
  f32x2 f;
  f = (f32x2){lo16f(qq.x), hi16f(qq.x)}; acc2[0] = pkfma(wv2, f, acc2[0]);
  f = (f32x2){lo16f(qq.y), hi16f(qq.y)}; acc2[1] = pkfma(wv2, f, acc2[1]);
  f = (f32x2){lo16f(qq.z), hi16f(qq.z)}; acc2[2] = pkfma(wv2, f, acc2[2]);
  f = (f32x2){lo16f(qq.w), hi16f(qq.w)}; acc2[3] = pkfma(wv2, f, acc2[3]);
}

// edge layout: [src(E) | dst(E)] halves, int32 (validated R11)

// ---------------- merged degree + k1 (independent work, one launch) ----------------
// blocks 0..1023: degree role, XCD-sharded by dst range (mapping identical to the
// standalone 1024-block launch). blocks 1024..1535: k1 MFMA role (512 blocks).

__global__ __launch_bounds__(256) void k_deg_k1(
    const int* __restrict__ ew, int* __restrict__ deg, int E, int nN,
    const float* __restrict__ x, const float* __restrict__ W1,
    const float* __restrict__ attS, const float* __restrict__ attD,
    bf16* __restrict__ hB, float* __restrict__ alS, float* __restrict__ alD) {
  if (blockIdx.x < 1024) {
    // ---- degree role ----
    int xcd = blockIdx.x & 7;
    int gb = blockIdx.x >> 3;
    int nBlk = 128;
    int nPer = (nN + 7) >> 3;
    int lo = xcd * nPer, hi = min(nN, lo + nPer);
    const int* dst = ew + E;
    for (int e = gb * 256 + threadIdx.x; e < E; e += nBlk * 256) {
      int d = dst[e];
      if (d >= lo && d < hi) atomicAdd(&deg[d], 1);
    }
    return;
  }
  // ---- k1 role: MFMA 16x16x32 bf16, wave per 16-node tile ----
  int lane = threadIdx.x & 63;
  int m = lane & 15;
  int q = lane >> 4;
  int wid = ((blockIdx.x - 1024) * 256 + threadIdx.x) >> 6;
  int nW = 512 * 4;
  bf16x8 wf[8][2];
  #pragma unroll
  for (int ct = 0; ct < 8; ++ct)
    #pragma unroll
    for (int ks = 0; ks < 2; ++ks)
      #pragma unroll
      for (int j = 0; j < 8; ++j)
        wf[ct][ks][j] = f2bs(W1[(ks * 32 + q * 8 + j) * C1 + ct * 16 + m]);
  float aS[8], aD[8];
  #pragma unroll
  for (int ct = 0; ct < 8; ++ct) {
    int g = ct >> 1;
    int cc = (ct & 1) * 16 + m;
    aS[ct] = attS[g * HID + cc];
    aD[ct] = attD[g * HID + cc];
  }
  int nT = nN >> 4;
  for (int nt = wid; nt < nT; nt += nW) {
    int n0 = nt * 16;
    const float* xr = x + (size_t)(n0 + m) * IN_CH;
    bf16x8 af[2];
    #pragma unroll
    for (int ks = 0; ks < 2; ++ks) {
      float4 v0 = *(const float4*)(xr + ks * 32 + q * 8);
      float4 v1 = *(const float4*)(xr + ks * 32 + q * 8 + 4);
      af[ks][0] = f2bs(v0.x); af[ks][1] = f2bs(v0.y);
      af[ks][2] = f2bs(v0.z); af[ks][3] = f2bs(v0.w);
      af[ks][4] = f2bs(v1.x); af[ks][5] = f2bs(v1.y);
      af[ks][6] = f2bs(v1.z); af[ks][7] = f2bs(v1.w);
    }
    f32x4 acc[8];
    #pragma unroll
    for (int ct = 0; ct < 8; ++ct) acc[ct] = (f32x4){0.f, 0.f, 0.f, 0.f};
    #pragma unroll
    for (int ct = 0; ct < 8; ++ct) {
      acc[ct] = __builtin_amdgcn_mfma_f32_16x16x32_bf16(af[0], wf[ct][0], acc[ct], 0, 0, 0);
      acc[ct] = __builtin_amdgcn_mfma_f32_16x16x32_bf16(af[1], wf[ct][1], acc[ct], 0, 0, 0);
    }
    float pS[4][4], pD[4][4];
    #pragma unroll
    for (int g = 0; g < 4; ++g)
      #pragma unroll
      for (int r = 0; r < 4; ++r) { pS[g][r] = 0.f; pD[g][r] = 0.f; }
    #pragma unroll
    for (int ct = 0; ct < 8; ++ct) {
      int g = ct >> 1;
      #pragma unroll
      for (int r = 0; r < 4; ++r) {
        float v = acc[ct][r];
        hB[(size_t)(n0 + q * 4 + r) * C1 + ct * 16 + m] = __float2bfloat16(v);
        pS[g][r] += v * aS[ct];
        pD[g][r] += v * aD[ct];
      }
    }
    #pragma unroll
    for (int off = 1; off < 16; off <<= 1) {
      #pragma unroll
      for (int g = 0; g < 4; ++g)
        #pragma unroll
        for (int r = 0; r < 4; ++r) {
          pS[g][r] += __shfl_xor(pS[g][r], off);
          pD[g][r] += __shfl_xor(pD[g][r], off);
        }
    }
    if (m == 0) {
      #pragma unroll
      for (int r = 0; r < 4; ++r) {
        int n = n0 + q * 4 + r;
        #pragma unroll
        for (int g = 0; g < 4; ++g) {
          alS[(size_t)n * 4 + g] = pS[g][r];
          alD[(size_t)n * 4 + g] = pD[g][r];
        }
      }
    }
  }
}

// ---------------- scans (unchanged) ----------------

__global__ void k_scan1(const int* __restrict__ deg, int* __restrict__ rp,
                        int* __restrict__ bsums, int n) {
  __shared__ int sm[256];
  int t = threadIdx.x;
  int i = blockIdx.x * 256 + t;
  int v = (i < n) ? deg[i] : 0;
  sm[t] = v;
  __syncthreads();
  #pragma unroll
  for (int off = 1; off < 256; off <<= 1) {
    int tv = (t >= off) ? sm[t - off] : 0;
    __syncthreads();
    sm[t] += tv;
    __syncthreads();
  }
  if (i < n) rp[i] = sm[t] - v;
  if (t == 255) bsums[blockIdx.x] = sm[255];
}

__global__ void k_scan2(int* __restrict__ bs, int nc) {
  __shared__ int sm[512];
  int t = threadIdx.x;
  int v = (t < nc) ? bs[t] : 0;
  sm[t] = v;
  __syncthreads();
  #pragma unroll
  for (int off = 1; off < 512; off <<= 1) {
    int tv = (t >= off) ? sm[t - off] : 0;
    __syncthreads();
    sm[t] += tv;
    __syncthreads();
  }
  if (t < nc) bs[t] = sm[t] - v;
}

__global__ void k_scan3(int* __restrict__ rp, int* __restrict__ cur,
                        const int* __restrict__ bs, int n, int E) {
  int i = blockIdx.x * 256 + threadIdx.x;
  if (i < n) {
    int r = rp[i] + bs[blockIdx.x];
    rp[i] = r;
    cur[i] = r;
  }
  if (i == 0) rp[n] = E;
}

__global__ __launch_bounds__(256) void k_scatter(const int* __restrict__ w,
                                                 int* __restrict__ cur,
                                                 int* __restrict__ csr, int E, int nN) {
  int xcd = blockIdx.x & 7;
  int gb = blockIdx.x >> 3;
  int nBlk = gridDim.x >> 3;
  int nPer = (nN + 7) >> 3;
  int lo = xcd * nPer, hi = min(nN, lo + nPer);
  const int* src = w;
  const int* dst = w + E;
  for (int e = gb * 256 + threadIdx.x; e < E; e += nBlk * 256) {
    int d = dst[e];
    if (d >= lo && d < hi) {
      int p = atomicAdd(&cur[d], 1);
      csr[p] = src[e];
    }
  }
}

// ---------------- k2 (R19): (node, head, quarter) + pipelined gather + pk-fma ----------
__global__ __launch_bounds__(256) void k2(
    const unsigned* __restrict__ hb, const float* __restrict__ alS, const float* __restrict__ alD,
    const int* __restrict__ rp, const int* __restrict__ csr,
    const float* __restrict__ b1, const float* __restrict__ W2,
    const float* __restrict__ attS2, const float* __restrict__ attD2,
    bf16* __restrict__ h2B, float* __restrict__ alS2, float* __restrict__ alD2, int nN) {
  __shared__ float w2s[C1 * OUTC];  // 16 KB
  for (int i = threadIdx.x; i < C1 * OUTC; i += 256) {
    int k = i >> 5;
    int ch = i & 31;
    int ch4 = ch >> 2;
    int cl = ch & 3;
    int sw = k >> 5;  // head index of this row, 0..3
    w2s[(k << 5) + (((ch4 ^ sw) << 2) | cl)] = W2[i];
  }
  __syncthreads();
  int t = blockIdx.x * 256 + threadIdx.x;  // grid is exactly nN*16 threads
  int n = t >> 4;
  int g = t & 3;
  int qt = (t >> 2) & 3;
  int rs = rp[n], re = rp[n + 1];
  float ad = alD[(size_t)n * HEADS + g];
  f32x2 acc2[16];
  #pragma unroll
  for (int j = 0; j < 16; ++j) acc2[j] = (f32x2){0.f, 0.f};
  float denom = 0.f;
  if (qt == 0) {  // self-loop handled by quarter 0
    float wv = __expf(lrelu(alS[(size_t)n * HEADS + g] + ad));
    denom += wv;
    const uint4* hr = (const uint4*)(hb + (size_t)n * 64 + g * 16);
    uint4 s0 = hr[0], s1 = hr[1], s2 = hr[2], s3 = hr[3];
    f32x2 wv2 = {wv, wv};
    mac4(acc2 + 0, wv2, s0); mac4(acc2 + 4, wv2, s1);
    mac4(acc2 + 8, wv2, s2); mac4(acc2 + 12, wv2, s3);
  }
  // pipelined edge loop: load edge i+4's data while computing edge i
  int i = rs + qt;
  if (i < re) {
    int sC = csr[i];
    float alC = alS[(size_t)sC * 4 + g];
    const uint4* hr = (const uint4*)(hb + (size_t)sC * 64 + g * 16);
    uint4 c0 = hr[0], c1 = hr[1], c2 = hr[2], c3 = hr[3];
    for (i += 4; i < re; i += 4) {
      int sN = csr[i];
      float alN = alS[(size_t)sN * 4 + g];
      const uint4* hn = (const uint4*)(hb + (size_t)sN * 64 + g * 16);
      uint4 n0 = hn[0], n1 = hn[1], n2 = hn[2], n3 = hn[3];
      float wv = __expf(lrelu(alC + ad));
      denom += wv;
      f32x2 wv2 = {wv, wv};
      mac4(acc2 + 0, wv2, c0); mac4(acc2 + 4, wv2, c1);
      mac4(acc2 + 8, wv2, c2); mac4(acc2 + 12, wv2, c3);
      alC = alN; c0 = n0; c1 = n1; c2 = n2; c3 = n3;
    }
    float wv = __expf(lrelu(alC + ad));
    denom += wv;
    f32x2 wv2 = {wv, wv};
    mac4(acc2 + 0, wv2, c0); mac4(acc2 + 4, wv2, c1);
    mac4(acc2 + 8, wv2, c2); mac4(acc2 + 12, wv2, c3);
  }
  // reduce over quarters (lane bits 2,3)
  denom += __shfl_xor(denom, 4);
  denom += __shfl_xor(denom, 8);
  #pragma unroll
  for (int j = 0; j < 16; ++j) {
    float a0 = acc2[j][0], a1 = acc2[j][1];
    a0 += __shfl_xor(a0, 4); a0 += __shfl_xor(a0, 8);
    a1 += __shfl_xor(a1, 4); a1 += __shfl_xor(a1, 8);
    acc2[j][0] = a0; acc2[j][1] = a1;
  }
  float inv = 1.f / denom;
  float bb[HID];
  {
    const float4* b1v = (const float4*)(b1 + g * HID);
    #pragma unroll
    for (int k4i = 0; k4i < 8; ++k4i) *(float4*)&bb[k4i * 4] = b1v[k4i];
  }
  float acc[HID];
  #pragma unroll
  for (int c = 0; c < HID; ++c)
    acc[c] = elu(acc2[c >> 1][c & 1] * inv + bb[c]);
  // fused layer-2 GEMM: j in [qt*8, qt*8+8) over this head's 32 k (packed FMAs)
  f32x2 pw[4];
  #pragma unroll
  for (int j = 0; j < 4; ++j) pw[j] = (f32x2){0.f, 0.f};
  #pragma unroll
  for (int kk = 0; kk < HID; ++kk) {
    float v = acc[kk];
    f32x2 v2 = {v, v};
    int base = (g * HID + kk) << 5;
    float4 w0 = *(const float4*)&w2s[base + (((qt * 2 + 0) ^ g) << 2)];
    float4 w1 = *(const float4*)&w2s[base + (((qt * 2 + 1) ^ g) << 2)];
    pw[0] = pkfma(v2, (f32x2){w0.x, w0.y}, pw[0]);
    pw[1] = pkfma(v2, (f32x2){w0.z, w0.w}, pw[1]);
    pw[2] = pkfma(v2, (f32x2){w1.x, w1.y}, pw[2]);
    pw[3] = pkfma(v2, (f32x2){w1.z, w1.w}, pw[3]);
  }
  float partial[8];
  #pragma unroll
  for (int j = 0; j < 8; ++j) partial[j] = pw[j >> 1][j & 1];
  // reduce over heads (lane bits 0,1)
  #pragma unroll
  for (int j = 0; j < 8; ++j) {
    partial[j] += __shfl_xor(partial[j], 1);
    partial[j] += __shfl_xor(partial[j], 2);
  }
  // layer-2 logits: dot with att over this lane's j-range, reduce over quarters
  float a2s[8], a2d[8];
  {
    const float4* sv = (const float4*)(attS2 + qt * 8);
    *(float4*)&a2s[0] = sv[0]; *(float4*)&a2s[4] = sv[1];
    const float4* dv = (const float4*)(attD2 + qt * 8);
    *(float4*)&a2d[0] = dv[0]; *(float4*)&a2d[4] = dv[1];
  }
  float ps = 0.f, pd = 0.f;
  #pragma unroll
  for (int j = 0; j < 8; ++j) {
    ps += partial[j] * a2s[j];
    pd += partial[j] * a2d[j];
  }
  ps += __shfl_xor(ps, 4); ps += __shfl_xor(ps, 8);
  pd += __shfl_xor(pd, 4); pd += __shfl_xor(pd, 8);
  if ((t & 15) == 0) {
    alS2[n] = ps;
    alD2[n] = pd;
  }
  if (g == 0) {  // one writer per (node, quarter): 16B each, 64B contiguous per node
    uint4 uu;
    uu.x = pack2(partial[0], partial[1]);
    uu.y = pack2(partial[2], partial[3]);
    uu.z = pack2(partial[4], partial[5]);
    uu.w = pack2(partial[6], partial[7]);
    *reinterpret_cast<uint4*>(h2B + (size_t)n * OUTC + qt * 8) = uu;
  }
}

// ---------------- k4 (R19): (node, quarter) + pipelined gather + pk-fma ----------
__global__ __launch_bounds__(256) void k4(
    const unsigned* __restrict__ h2b, const float* __restrict__ alS2,
    const float* __restrict__ alD2, const int* __restrict__ rp, const int* __restrict__ csr,
    const float* __restrict__ b2, float* __restrict__ out, int nN) {
  int t = blockIdx.x * 256 + threadIdx.x;
  if (t >= nN * 4) return;
  int n = t >> 2;
  int qt = t & 3;
  int rs = rp[n], re = rp[n + 1];
  float ad = alD2[n];
  f32x2 acc2[16];
  #pragma unroll
  for (int j = 0; j < 16; ++j) acc2[j] = (f32x2){0.f, 0.f};
  float denom = 0.f;
  if (qt == 0) {  // self-loop
    float wv = __expf(lrelu(alS2[n] + ad));
    denom += wv;
    const uint4* hr = (const uint4*)(h2b + (size_t)n * 16);
    uint4 s0 = hr[0], s1 = hr[1], s2 = hr[2], s3 = hr[3];
    f32x2 wv2 = {wv, wv};
    mac4(acc2 + 0, wv2, s0); mac4(acc2 + 4, wv2, s1);
    mac4(acc2 + 8, wv2, s2); mac4(acc2 + 12, wv2, s3);
  }
  int i = rs + qt;
  if (i < re) {
    int sC = csr[i];
    float alC = alS2[sC];
    const uint4* hr = (const uint4*)(h2b + (size_t)sC * 16);
    uint4 c0 = hr[0], c1 = hr[1], c2 = hr[2], c3 = hr[3];
    for (i += 4; i < re; i += 4) {
      int sN = csr[i];
      float alN = alS2[sN];
      const uint4* hn = (const uint4*)(h2b + (size_t)sN * 16);
      uint4 n0 = hn[0], n1 = hn[1], n2 = hn[2], n3 = hn[3];
      float wv = __expf(lrelu(alC + ad));
      denom += wv;
      f32x2 wv2 = {wv, wv};
      mac4(acc2 + 0, wv2, c0); mac4(acc2 + 4, wv2, c1);
      mac4(acc2 + 8, wv2, c2); mac4(acc2 + 12, wv2, c3);
      alC = alN; c0 = n0; c1 = n1; c2 = n2; c3 = n3;
    }
    float wv = __expf(lrelu(alC + ad));
    denom += wv;
    f32x2 wv2 = {wv, wv};
    mac4(acc2 + 0, wv2, c0); mac4(acc2 + 4, wv2, c1);
    mac4(acc2 + 8, wv2, c2); mac4(acc2 + 12, wv2, c3);
  }
  // reduce over quarters (lane bits 0,1)
  denom += __shfl_xor(denom, 1);
  denom += __shfl_xor(denom, 2);
  #pragma unroll
  for (int j = 0; j < 16; ++j) {
    float a0 = acc2[j][0], a1 = acc2[j][1];
    a0 += __shfl_xor(a0, 1); a0 += __shfl_xor(a0, 2);
    a1 += __shfl_xor(a1, 1); a1 += __shfl_xor(a1, 2);
    acc2[j][0] = a0; acc2[j][1] = a1;
  }
  float inv = 1.f / denom;
  float bb[8];
  {
    const float4* b2v = (const float4*)(b2 + qt * 8);
    *(float4*)&bb[0] = b2v[0]; *(float4*)&bb[4] = b2v[1];
  }
  int j0 = qt * 4;  // acc2 pair-index base for channels [qt*8, qt*8+8)
  float4 o0, o1;
  o0.x = acc2[j0 + 0][0] * inv + bb[0];
  o0.y = acc2[j0 + 0][1] * inv + bb[1];
  o0.z = acc2[j0 + 1][0] * inv + bb[2];
  o0.w = acc2[j0 + 1][1] * inv + bb[3];
  o1.x = acc2[j0 + 2][0] * inv + bb[4];
  o1.y = acc2[j0 + 2][1] * inv + bb[5];
  o1.z = acc2[j0 + 3][0] * inv + bb[6];
  o1.w = acc2[j0 + 3][1] * inv + bb[7];
  *(float4*)(out + (size_t)n * OUTC + qt * 8) = o0;
  *(float4*)(out + (size_t)n * OUTC + qt * 8 + 4) = o1;
}

// ---------------- launch ----------------

extern "C" void kernel_launch(void* const* d_in, const int* in_sizes, int n_in,
                              void* d_out, int out_size, void* d_ws, size_t ws_size,
                              hipStream_t stream) {
  {
    const int expect[10] = {6400000, 3200000, 8192, 128, 128, 128, 4096, 32, 32, 32};
    bool ok = (n_in == 10) && (out_size == 3200000);
    for (int i = 0; i < 10 && ok; ++i) ok = (in_sizes[i] == expect[i]);
    if (!ok) { *(volatile int*)0 = 1; }
  }

  const float* x     = (const float*)d_in[0];
  const int*   ew    = (const int*)d_in[1];
  const float* W1    = (const float*)d_in[2];
  const float* attS1 = (const float*)d_in[3];
  const float* attD1 = (const float*)d_in[4];
  const float* b1    = (const float*)d_in[5];
  const float* W2    = (const float*)d_in[6];
  const float* attS2 = (const float*)d_in[7];
  const float* attD2 = (const float*)d_in[8];
  const float* b2    = (const float*)d_in[9];
  float* out = (float*)d_out;

  const int nN = in_sizes[0] / IN_CH;   // 100000
  const int E  = in_sizes[1] / 2;       // 1600000

  auto ALN = [](size_t v) { return (v + 255) & ~(size_t)255; };
  char* p = (char*)d_ws;
  bf16*  hB   = (bf16*)p;  p += ALN((size_t)nN * C1 * 2);
  float* alS1v= (float*)p; p += ALN((size_t)nN * 4 * 4);
  float* alD1v= (float*)p; p += ALN((size_t)nN * 4 * 4);
  bf16*  h2B  = (bf16*)p;  p += ALN((size_t)nN * OUTC * 2);
  float* alS2v= (float*)p; p += ALN((size_t)nN * 4);
  float* alD2v= (float*)p; p += ALN((size_t)nN * 4);
  int* deg    = (int*)p;   p += ALN((size_t)nN * 4);
  int* rp     = (int*)p;   p += ALN((size_t)(nN + 1) * 4);
  int* cur    = (int*)p;   p += ALN((size_t)nN * 4);
  int* bs     = (int*)p;   p += ALN(1024 * 4);
  int* csr    = (int*)p;   p += ALN((size_t)E * 4);
  if ((size_t)(p - (char*)d_ws) > ws_size) { *(volatile int*)0 = 2; }

  const int nChunks = (nN + 255) / 256;  // 391

  hipMemsetAsync(deg, 0, (size_t)nN * 4, stream);
  k_deg_k1<<<1536, 256, 0, stream>>>(ew, deg, E, nN,
                                     x, W1, attS1, attD1, hB, alS1v, alD1v);
  k_scan1<<<nChunks, 256, 0, stream>>>(deg, rp, bs, nN);
  k_scan2<<<1, 512, 0, stream>>>(bs, nChunks);
  k_scan3<<<nChunks, 256, 0, stream>>>(rp, cur, bs, nN, E);
  k_scatter<<<1024, 256, 0, stream>>>(ew, cur, csr, E, nN);
  k2<<<(nN * 16) / 256, 256, 0, stream>>>((const unsigned*)hB, alS1v, alD1v,
                                          rp, csr, b1, W2, attS2, attD2,
                                          h2B, alS2v, alD2v, nN);
  k4<<<(nN * 4 + 255) / 256, 256, 0, stream>>>((const unsigned*)h2B, alS2v, alD2v,
                                               rp, csr, b2, out, nN);
}

// Round 5
// 367.364 us; speedup vs baseline: 1.2034x; 1.0235x over previous
//
#include <hip/hip_runtime.h>
#include <hip/hip_bf16.h>

typedef __hip_bfloat16 bf16;
typedef short bf16x8 __attribute__((ext_vector_type(8)));
typedef float f32x4 __attribute__((ext_vector_type(4)));

#define IN_CH 64
#define HID 32
#define HEADS 4
#define C1 128   // HEADS*HID
#define OUTC 32
#define NEGSLOPE 0.2f

__device__ __forceinline__ float lrelu(float v) { return v > 0.f ? v : NEGSLOPE * v; }
__device__ __forceinline__ float elu(float v) { return v > 0.f ? v : __expf(v) - 1.f; }
__device__ __forceinline__ float lo16f(unsigned u) { return __uint_as_float(u << 16); }
__device__ __forceinline__ float hi16f(unsigned u) { return __uint_as_float(u & 0xFFFF0000u); }
__device__ __forceinline__ short f2bs(float f) {
  bf16 b = __float2bfloat16(f);
  return *reinterpret_cast<short*>(&b);
}
__device__ __forceinline__ unsigned pack2(float lo, float hi) {
  unsigned short l = (unsigned short)f2bs(lo);
  unsigned short h = (unsigned short)f2bs(hi);
  return ((unsigned)h << 16) | (unsigned)l;
}
// acc[0..7] += wv * unpack8(qq)
__device__ __forceinline__ void mac8(float* acc, float wv, uint4 qq) {
  acc[0] += wv * lo16f(qq.x); acc[1] += wv * hi16f(qq.x);
  acc[2] += wv * lo16f(qq.y); acc[3] += wv * hi16f(qq.y);
  acc[4] += wv * lo16f(qq.z); acc[5] += wv * hi16f(qq.z);
  acc[6] += wv * lo16f(qq.w); acc[7] += wv * hi16f(qq.w);
}

// edge layout: [src(E) | dst(E)] halves, int32 (validated R11)

// ---------------- merged degree + k1 (validated R19) ----------------
// blocks 0..1023: degree role, XCD-sharded by dst range.
// blocks 1024..1535: k1 MFMA role (512 blocks).

__global__ __launch_bounds__(256) void k_deg_k1(
    const int* __restrict__ ew, int* __restrict__ deg, int E, int nN,
    const float* __restrict__ x, const float* __restrict__ W1,
    const float* __restrict__ attS, const float* __restrict__ attD,
    bf16* __restrict__ hB, float* __restrict__ alS, float* __restrict__ alD) {
  if (blockIdx.x < 1024) {
    // ---- degree role ----
    int xcd = blockIdx.x & 7;
    int gb = blockIdx.x >> 3;
    int nBlk = 128;
    int nPer = (nN + 7) >> 3;
    int lo = xcd * nPer, hi = min(nN, lo + nPer);
    const int* dst = ew + E;
    for (int e = gb * 256 + threadIdx.x; e < E; e += nBlk * 256) {
      int d = dst[e];
      if (d >= lo && d < hi) atomicAdd(&deg[d], 1);
    }
    return;
  }
  // ---- k1 role: MFMA 16x16x32 bf16, wave per 16-node tile ----
  int lane = threadIdx.x & 63;
  int m = lane & 15;
  int q = lane >> 4;
  int wid = ((blockIdx.x - 1024) * 256 + threadIdx.x) >> 6;
  int nW = 512 * 4;
  bf16x8 wf[8][2];
  #pragma unroll
  for (int ct = 0; ct < 8; ++ct)
    #pragma unroll
    for (int ks = 0; ks < 2; ++ks)
      #pragma unroll
      for (int j = 0; j < 8; ++j)
        wf[ct][ks][j] = f2bs(W1[(ks * 32 + q * 8 + j) * C1 + ct * 16 + m]);
  float aS[8], aD[8];
  #pragma unroll
  for (int ct = 0; ct < 8; ++ct) {
    int g = ct >> 1;
    int cc = (ct & 1) * 16 + m;
    aS[ct] = attS[g * HID + cc];
    aD[ct] = attD[g * HID + cc];
  }
  int nT = nN >> 4;
  for (int nt = wid; nt < nT; nt += nW) {
    int n0 = nt * 16;
    const float* xr = x + (size_t)(n0 + m) * IN_CH;
    bf16x8 af[2];
    #pragma unroll
    for (int ks = 0; ks < 2; ++ks) {
      float4 v0 = *(const float4*)(xr + ks * 32 + q * 8);
      float4 v1 = *(const float4*)(xr + ks * 32 + q * 8 + 4);
      af[ks][0] = f2bs(v0.x); af[ks][1] = f2bs(v0.y);
      af[ks][2] = f2bs(v0.z); af[ks][3] = f2bs(v0.w);
      af[ks][4] = f2bs(v1.x); af[ks][5] = f2bs(v1.y);
      af[ks][6] = f2bs(v1.z); af[ks][7] = f2bs(v1.w);
    }
    f32x4 acc[8];
    #pragma unroll
    for (int ct = 0; ct < 8; ++ct) acc[ct] = (f32x4){0.f, 0.f, 0.f, 0.f};
    #pragma unroll
    for (int ct = 0; ct < 8; ++ct) {
      acc[ct] = __builtin_amdgcn_mfma_f32_16x16x32_bf16(af[0], wf[ct][0], acc[ct], 0, 0, 0);
      acc[ct] = __builtin_amdgcn_mfma_f32_16x16x32_bf16(af[1], wf[ct][1], acc[ct], 0, 0, 0);
    }
    float pS[4][4], pD[4][4];
    #pragma unroll
    for (int g = 0; g < 4; ++g)
      #pragma unroll
      for (int r = 0; r < 4; ++r) { pS[g][r] = 0.f; pD[g][r] = 0.f; }
    #pragma unroll
    for (int ct = 0; ct < 8; ++ct) {
      int g = ct >> 1;
      #pragma unroll
      for (int r = 0; r < 4; ++r) {
        float v = acc[ct][r];
        hB[(size_t)(n0 + q * 4 + r) * C1 + ct * 16 + m] = __float2bfloat16(v);
        pS[g][r] += v * aS[ct];
        pD[g][r] += v * aD[ct];
      }
    }
    #pragma unroll
    for (int off = 1; off < 16; off <<= 1) {
      #pragma unroll
      for (int g = 0; g < 4; ++g)
        #pragma unroll
        for (int r = 0; r < 4; ++r) {
          pS[g][r] += __shfl_xor(pS[g][r], off);
          pD[g][r] += __shfl_xor(pD[g][r], off);
        }
    }
    if (m == 0) {
      #pragma unroll
      for (int r = 0; r < 4; ++r) {
        int n = n0 + q * 4 + r;
        #pragma unroll
        for (int g = 0; g < 4; ++g) {
          alS[(size_t)n * 4 + g] = pS[g][r];
          alD[(size_t)n * 4 + g] = pD[g][r];
        }
      }
    }
  }
}

// ---------------- scans (unchanged) ----------------

__global__ void k_scan1(const int* __restrict__ deg, int* __restrict__ rp,
                        int* __restrict__ bsums, int n) {
  __shared__ int sm[256];
  int t = threadIdx.x;
  int i = blockIdx.x * 256 + t;
  int v = (i < n) ? deg[i] : 0;
  sm[t] = v;
  __syncthreads();
  #pragma unroll
  for (int off = 1; off < 256; off <<= 1) {
    int tv = (t >= off) ? sm[t - off] : 0;
    __syncthreads();
    sm[t] += tv;
    __syncthreads();
  }
  if (i < n) rp[i] = sm[t] - v;
  if (t == 255) bsums[blockIdx.x] = sm[255];
}

__global__ void k_scan2(int* __restrict__ bs, int nc) {
  __shared__ int sm[512];
  int t = threadIdx.x;
  int v = (t < nc) ? bs[t] : 0;
  sm[t] = v;
  __syncthreads();
  #pragma unroll
  for (int off = 1; off < 512; off <<= 1) {
    int tv = (t >= off) ? sm[t - off] : 0;
    __syncthreads();
    sm[t] += tv;
    __syncthreads();
  }
  if (t < nc) bs[t] = sm[t] - v;
}

__global__ void k_scan3(int* __restrict__ rp, int* __restrict__ cur,
                        const int* __restrict__ bs, int n, int E) {
  int i = blockIdx.x * 256 + threadIdx.x;
  if (i < n) {
    int r = rp[i] + bs[blockIdx.x];
    rp[i] = r;
    cur[i] = r;
  }
  if (i == 0) rp[n] = E;
}

__global__ __launch_bounds__(256) void k_scatter(const int* __restrict__ w,
                                                 int* __restrict__ cur,
                                                 int* __restrict__ csr, int E, int nN) {
  int xcd = blockIdx.x & 7;
  int gb = blockIdx.x >> 3;
  int nBlk = gridDim.x >> 3;
  int nPer = (nN + 7) >> 3;
  int lo = xcd * nPer, hi = min(nN, lo + nPer);
  const int* src = w;
  const int* dst = w + E;
  for (int e = gb * 256 + threadIdx.x; e < E; e += nBlk * 256) {
    int d = dst[e];
    if (d >= lo && d < hi) {
      int p = atomicAdd(&cur[d], 1);
      csr[p] = src[e];
    }
  }
}

// ---------------- k2 (R20): cooperative coalesced gather ----------------
// 16 lanes per node: c4 = lane&3 (16B chunk of the 256B hB row), qt = (lane>>2)&3
// (edge quarter). Per edge, the 4 c4-lanes read ONE contiguous 64B line per
// instruction (addr = s*256 + k*64 + c4*16) -> TA merges to 1 L2 request:
// 4 requests/edge for hB vs 16 in R18. Chunk k holds channels [32k+8c4,+8)
// which lie entirely in head k, so lane c4 computes head c4's exp (exp count
// unchanged: 4 per edge) and gets the other heads' weights via __shfl within
// the aligned 4-lane group.
__global__ __launch_bounds__(256) void k2(
    const unsigned* __restrict__ hb, const float* __restrict__ alS, const float* __restrict__ alD,
    const int* __restrict__ rp, const int* __restrict__ csr,
    const float* __restrict__ b1, const float* __restrict__ W2,
    const float* __restrict__ attS2, const float* __restrict__ attD2,
    bf16* __restrict__ h2B, float* __restrict__ alS2, float* __restrict__ alD2, int nN) {
  __shared__ float w2s[C1 * OUTC];  // 16 KB, plain layout (access is conflict-free)
  for (int i = threadIdx.x; i < C1 * OUTC; i += 256) w2s[i] = W2[i];
  __syncthreads();
  int t = blockIdx.x * 256 + threadIdx.x;  // grid is exactly nN*16 threads
  int n = t >> 4;
  int l16 = t & 15;
  int c4 = l16 & 3;
  int qt = l16 >> 2;
  int lane = threadIdx.x & 63;
  int base4 = lane & ~3;
  int rs = rp[n], re = rp[n + 1];
  float ad = alD[(size_t)n * HEADS + c4];  // dst logit for head c4
  float acc[4][8];
  #pragma unroll
  for (int k = 0; k < 4; ++k)
    #pragma unroll
    for (int c = 0; c < 8; ++c) acc[k][c] = 0.f;
  float denom = 0.f;
  if (qt == 0) {  // self-loop handled by quarter 0
    float wv = __expf(lrelu(alS[(size_t)n * HEADS + c4] + ad));
    denom += wv;
    float w0 = __shfl(wv, base4 + 0);
    float w1 = __shfl(wv, base4 + 1);
    float w2v = __shfl(wv, base4 + 2);
    float w3 = __shfl(wv, base4 + 3);
    const unsigned* row = hb + (size_t)n * 64 + c4 * 4;
    uint4 q0 = *(const uint4*)(row + 0);
    uint4 q1 = *(const uint4*)(row + 16);
    uint4 q2 = *(const uint4*)(row + 32);
    uint4 q3 = *(const uint4*)(row + 48);
    mac8(acc[0], w0, q0); mac8(acc[1], w1, q1);
    mac8(acc[2], w2v, q2); mac8(acc[3], w3, q3);
  }
  for (int i = rs + qt; i < re; i += 4) {
    int s = csr[i];
    float a = alS[(size_t)s * HEADS + c4];
    const unsigned* row = hb + (size_t)s * 64 + c4 * 4;
    uint4 q0 = *(const uint4*)(row + 0);
    uint4 q1 = *(const uint4*)(row + 16);
    uint4 q2 = *(const uint4*)(row + 32);
    uint4 q3 = *(const uint4*)(row + 48);
    float wv = __expf(lrelu(a + ad));
    denom += wv;
    float w0 = __shfl(wv, base4 + 0);
    float w1 = __shfl(wv, base4 + 1);
    float w2v = __shfl(wv, base4 + 2);
    float w3 = __shfl(wv, base4 + 3);
    mac8(acc[0], w0, q0); mac8(acc[1], w1, q1);
    mac8(acc[2], w2v, q2); mac8(acc[3], w3, q3);
  }
  // reduce over edge quarters (lane bits 2,3)
  denom += __shfl_xor(denom, 4);
  denom += __shfl_xor(denom, 8);
  #pragma unroll
  for (int k = 0; k < 4; ++k)
    #pragma unroll
    for (int c = 0; c < 8; ++c) {
      acc[k][c] += __shfl_xor(acc[k][c], 4);
      acc[k][c] += __shfl_xor(acc[k][c], 8);
    }
  // per-head denominators (lane's denom is head c4's)
  float dk[4];
  dk[0] = __shfl(denom, base4 + 0);
  dk[1] = __shfl(denom, base4 + 1);
  dk[2] = __shfl(denom, base4 + 2);
  dk[3] = __shfl(denom, base4 + 3);
  // normalize + bias + ELU; lane's channels: ch = 32k + 8*c4 + c (head k)
  #pragma unroll
  for (int k = 0; k < 4; ++k) {
    float inv = 1.f / dk[k];
    float4 ba = *(const float4*)(b1 + 32 * k + 8 * c4);
    float4 bb = *(const float4*)(b1 + 32 * k + 8 * c4 + 4);
    acc[k][0] = elu(acc[k][0] * inv + ba.x);
    acc[k][1] = elu(acc[k][1] * inv + ba.y);
    acc[k][2] = elu(acc[k][2] * inv + ba.z);
    acc[k][3] = elu(acc[k][3] * inv + ba.w);
    acc[k][4] = elu(acc[k][4] * inv + bb.x);
    acc[k][5] = elu(acc[k][5] * inv + bb.y);
    acc[k][6] = elu(acc[k][6] * inv + bb.z);
    acc[k][7] = elu(acc[k][7] * inv + bb.w);
  }
  // fused layer-2 GEMM: lane computes j in [qt*8, qt*8+8) over its 32 channels.
  // LDS access per instr: 4 distinct addresses (by qt) + broadcast -> conflict-free.
  float partial[8];
  #pragma unroll
  for (int j = 0; j < 8; ++j) partial[j] = 0.f;
  #pragma unroll
  for (int k = 0; k < 4; ++k)
    #pragma unroll
    for (int c = 0; c < 8; ++c) {
      float v = acc[k][c];
      int ch = 32 * k + 8 * c4 + c;
      const float4* wr = (const float4*)&w2s[ch * 32 + qt * 8];
      float4 wa = wr[0], wb = wr[1];
      partial[0] += v * wa.x; partial[1] += v * wa.y;
      partial[2] += v * wa.z; partial[3] += v * wa.w;
      partial[4] += v * wb.x; partial[5] += v * wb.y;
      partial[6] += v * wb.z; partial[7] += v * wb.w;
    }
  // reduce over channel-chunk groups (lane bits 0,1)
  #pragma unroll
  for (int j = 0; j < 8; ++j) {
    partial[j] += __shfl_xor(partial[j], 1);
    partial[j] += __shfl_xor(partial[j], 2);
  }
  // layer-2 logits: dot with att over this lane's j-range, reduce over quarters
  float a2s[8], a2d[8];
  {
    const float4* sv = (const float4*)(attS2 + qt * 8);
    *(float4*)&a2s[0] = sv[0]; *(float4*)&a2s[4] = sv[1];
    const float4* dv = (const float4*)(attD2 + qt * 8);
    *(float4*)&a2d[0] = dv[0]; *(float4*)&a2d[4] = dv[1];
  }
  float ps = 0.f, pd = 0.f;
  #pragma unroll
  for (int j = 0; j < 8; ++j) {
    ps += partial[j] * a2s[j];
    pd += partial[j] * a2d[j];
  }
  ps += __shfl_xor(ps, 4); ps += __shfl_xor(ps, 8);
  pd += __shfl_xor(pd, 4); pd += __shfl_xor(pd, 8);
  if (l16 == 0) {
    alS2[n] = ps;
    alD2[n] = pd;
  }
  if (c4 == 0) {  // one writer per (node, j-range): 16B each, 64B contiguous/node
    uint4 uu;
    uu.x = pack2(partial[0], partial[1]);
    uu.y = pack2(partial[2], partial[3]);
    uu.z = pack2(partial[4], partial[5]);
    uu.w = pack2(partial[6], partial[7]);
    *reinterpret_cast<uint4*>(h2B + (size_t)n * OUTC + qt * 8) = uu;
  }
}

// ---------------- k4 (R20): cooperative coalesced gather ----------------
// 16 lanes per node: c4 = lane&3 (16B chunk of the 64B h2b row), qt = edge
// quarter. Per edge the 4 c4-lanes read one contiguous 64B line (1 request).
__global__ __launch_bounds__(256) void k4(
    const unsigned* __restrict__ h2b, const float* __restrict__ alS2,
    const float* __restrict__ alD2, const int* __restrict__ rp, const int* __restrict__ csr,
    const float* __restrict__ b2, float* __restrict__ out, int nN) {
  int t = blockIdx.x * 256 + threadIdx.x;  // grid is exactly nN*16 threads
  int n = t >> 4;
  int l16 = t & 15;
  int c4 = l16 & 3;
  int qt = l16 >> 2;
  int rs = rp[n], re = rp[n + 1];
  float ad = alD2[n];
  float acc[8];
  #pragma unroll
  for (int c = 0; c < 8; ++c) acc[c] = 0.f;
  float denom = 0.f;
  if (qt == 0) {  // self-loop
    float wv = __expf(lrelu(alS2[n] + ad));
    denom += wv;
    uint4 qq = *(const uint4*)(h2b + (size_t)n * 16 + c4 * 4);
    mac8(acc, wv, qq);
  }
  for (int i = rs + qt; i < re; i += 4) {
    int s = csr[i];
    float a = alS2[s];
    uint4 qq = *(const uint4*)(h2b + (size_t)s * 16 + c4 * 4);
    float wv = __expf(lrelu(a + ad));
    denom += wv;
    mac8(acc, wv, qq);
  }
  // reduce over edge quarters (lane bits 2,3)
  denom += __shfl_xor(denom, 4);
  denom += __shfl_xor(denom, 8);
  #pragma unroll
  for (int c = 0; c < 8; ++c) {
    acc[c] += __shfl_xor(acc[c], 4);
    acc[c] += __shfl_xor(acc[c], 8);
  }
  if (qt == 0) {  // 4 writer lanes per node, 128B contiguous
    float inv = 1.f / denom;
    float4 ba = *(const float4*)(b2 + c4 * 8);
    float4 bb = *(const float4*)(b2 + c4 * 8 + 4);
    float4 o0, o1;
    o0.x = acc[0] * inv + ba.x;
    o0.y = acc[1] * inv + ba.y;
    o0.z = acc[2] * inv + ba.z;
    o0.w = acc[3] * inv + ba.w;
    o1.x = acc[4] * inv + bb.x;
    o1.y = acc[5] * inv + bb.y;
    o1.z = acc[6] * inv + bb.z;
    o1.w = acc[7] * inv + bb.w;
    *(float4*)(out + (size_t)n * OUTC + c4 * 8) = o0;
    *(float4*)(out + (size_t)n * OUTC + c4 * 8 + 4) = o1;
  }
}

// ---------------- launch ----------------

extern "C" void kernel_launch(void* const* d_in, const int* in_sizes, int n_in,
                              void* d_out, int out_size, void* d_ws, size_t ws_size,
                              hipStream_t stream) {
  {
    const int expect[10] = {6400000, 3200000, 8192, 128, 128, 128, 4096, 32, 32, 32};
    bool ok = (n_in == 10) && (out_size == 3200000);
    for (int i = 0; i < 10 && ok; ++i) ok = (in_sizes[i] == expect[i]);
    if (!ok) { *(volatile int*)0 = 1; }
  }

  const float* x     = (const float*)d_in[0];
  const int*   ew    = (const int*)d_in[1];
  const float* W1    = (const float*)d_in[2];
  const float* attS1 = (const float*)d_in[3];
  const float* attD1 = (const float*)d_in[4];
  const float* b1    = (const float*)d_in[5];
  const float* W2    = (const float*)d_in[6];
  const float* attS2 = (const float*)d_in[7];
  const float* attD2 = (const float*)d_in[8];
  const float* b2    = (const float*)d_in[9];
  float* out = (float*)d_out;

  const int nN = in_sizes[0] / IN_CH;   // 100000
  const int E  = in_sizes[1] / 2;       // 1600000

  auto ALN = [](size_t v) { return (v + 255) & ~(size_t)255; };
  char* p = (char*)d_ws;
  bf16*  hB   = (bf16*)p;  p += ALN((size_t)nN * C1 * 2);
  float* alS1v= (float*)p; p += ALN((size_t)nN * 4 * 4);
  float* alD1v= (float*)p; p += ALN((size_t)nN * 4 * 4);
  bf16*  h2B  = (bf16*)p;  p += ALN((size_t)nN * OUTC * 2);
  float* alS2v= (float*)p; p += ALN((size_t)nN * 4);
  float* alD2v= (float*)p; p += ALN((size_t)nN * 4);
  int* deg    = (int*)p;   p += ALN((size_t)nN * 4);
  int* rp     = (int*)p;   p += ALN((size_t)(nN + 1) * 4);
  int* cur    = (int*)p;   p += ALN((size_t)nN * 4);
  int* bs     = (int*)p;   p += ALN(1024 * 4);
  int* csr    = (int*)p;   p += ALN((size_t)E * 4);
  if ((size_t)(p - (char*)d_ws) > ws_size) { *(volatile int*)0 = 2; }

  const int nChunks = (nN + 255) / 256;  // 391

  hipMemsetAsync(deg, 0, (size_t)nN * 4, stream);
  k_deg_k1<<<1536, 256, 0, stream>>>(ew, deg, E, nN,
                                     x, W1, attS1, attD1, hB, alS1v, alD1v);
  k_scan1<<<nChunks, 256, 0, stream>>>(deg, rp, bs, nN);
  k_scan2<<<1, 512, 0, stream>>>(bs, nChunks);
  k_scan3<<<nChunks, 256, 0, stream>>>(rp, cur, bs, nN, E);
  k_scatter<<<1024, 256, 0, stream>>>(ew, cur, csr, E, nN);
  k2<<<(nN * 16) / 256, 256, 0, stream>>>((const unsigned*)hB, alS1v, alD1v,
                                          rp, csr, b1, W2, attS2, attD2,
                                          h2B, alS2v, alD2v, nN);
  k4<<<(nN * 16) / 256, 256, 0, stream>>>((const unsigned*)h2B, alS2v, alD2v,
                                          rp, csr, b2, out, nN);
}